// Round 1
// baseline (616.755 us; speedup 1.0000x reference)
//
#include <hip/hip_runtime.h>
#include <hip/hip_bf16.h>

// DownBlock: pool(mean over 7 down-neighbors) -> conv1(K=7, 32->64) -> BN+LReLU
//         -> conv2(K=7, 64->64) -> BN+LReLU
// B=16, C_IN=32, C=64, V_FINE=163842, V=40962, K=7.
// Biases b1/b2 are dead: BN's mean subtraction absorbs per-channel constants.

#define B_SZ     16
#define CIN      32
#define CMID     64
#define VFINE    163842
#define VC       40962
#define KNB      7

typedef __attribute__((ext_vector_type(8))) short  short8;   // 8 x bf16 (as i16)
typedef __attribute__((ext_vector_type(4))) float  f32x4;
typedef __attribute__((ext_vector_type(4))) unsigned short u16x4;
typedef __attribute__((ext_vector_type(2))) unsigned short u16x2;

__device__ inline float bf2f(unsigned short u) {
    return __builtin_bit_cast(float, (unsigned int)(((unsigned int)u) << 16));
}
__device__ inline unsigned short f2bf(float f) {
    __hip_bfloat16 h = __float2bfloat16(f);
    return __builtin_bit_cast(unsigned short, h);
}

// ---------------------------------------------------------------------------
// Prep: reorder W into per-lane MFMA A-fragments, bf16.
// Fragment (chunk, otile): lane l, elem j ->  A[o = otile*16 + (l&15)][kk = (l>>4)*8 + j]
// conv1: chunk cc = k (7 chunks), c = kk.        W1[o][c*7+k]
// conv2: chunk cc = k*2 + ch (14), c = ch*32+kk. W2[o][c*7+k]
// ---------------------------------------------------------------------------
__global__ void prep_w(const float* __restrict__ w1, const float* __restrict__ w2,
                       unsigned short* __restrict__ w1f, unsigned short* __restrict__ w2f) {
    int tid = blockIdx.x * blockDim.x + threadIdx.x;
    int stride = gridDim.x * blockDim.x;
    const int total1 = 7 * 4 * 64 * 8;
    for (int idx = tid; idx < total1; idx += stride) {
        int j = idx & 7, l = (idx >> 3) & 63, t = (idx >> 9) & 3, cc = idx >> 11;
        int o = t * 16 + (l & 15);
        int kk = (l >> 4) * 8 + j;
        w1f[idx] = f2bf(w1[o * 224 + kk * 7 + cc]);
    }
    const int total2 = 14 * 4 * 64 * 8;
    for (int idx = tid; idx < total2; idx += stride) {
        int j = idx & 7, l = (idx >> 3) & 63, t = (idx >> 9) & 3, cc = idx >> 11;
        int o = t * 16 + (l & 15);
        int kk = (l >> 4) * 8 + j;
        int k = cc >> 1, ch = cc & 1;
        int c = ch * 32 + kk;
        w2f[idx] = f2bf(w2[o * 448 + c * 7 + k]);
    }
}

// ---------------------------------------------------------------------------
// Transpose x (512 rows x VFINE) f32 -> xt[v][512] bf16. 16-vertex tile via LDS.
// ---------------------------------------------------------------------------
__global__ __launch_bounds__(256) void transpose_x(const float* __restrict__ x,
                                                   unsigned short* __restrict__ xt, int vf) {
    __shared__ float lds[16 * 516];
    const int t = threadIdx.x;
    const int v0 = blockIdx.x * 16;
    // load: rows 0..511, 16 vertices; coalesced 64B per row
    {
        int voff = t & 15, r0 = t >> 4;
        int v = v0 + voff;
        bool ok = (v < vf);
        for (int i = 0; i < 32; ++i) {
            int row = r0 + i * 16;
            lds[voff * 516 + row] = ok ? x[(size_t)row * vf + v] : 0.f;
        }
    }
    __syncthreads();
    // store: per-vertex contiguous 1KB (as ushort2)
    {
        int vv = t >> 4, c0 = t & 15;
        int v = v0 + vv;
        if (v < vf) {
            for (int j = 0; j < 16; ++j) {
                int f = c0 * 2 + 32 * j;
                u16x2 o2;
                o2[0] = f2bf(lds[vv * 516 + f]);
                o2[1] = f2bf(lds[vv * 516 + f + 1]);
                *reinterpret_cast<u16x2*>(xt + (size_t)v * 512 + f) = o2;
            }
        }
    }
}

// ---------------------------------------------------------------------------
// Pool: xp[v][b][c] = mean_k xt[dn[v][k]][b][c]. One wave per coarse vertex.
// ---------------------------------------------------------------------------
__global__ __launch_bounds__(256) void pool_k(const unsigned short* __restrict__ xt,
                                              const int* __restrict__ dn,
                                              unsigned short* __restrict__ xp, int vc) {
    int wid = (blockIdx.x * blockDim.x + threadIdx.x) >> 6;
    int lane = threadIdx.x & 63;
    if (wid >= vc) return;
    float acc[8];
#pragma unroll
    for (int j = 0; j < 8; ++j) acc[j] = 0.f;
#pragma unroll
    for (int k = 0; k < 7; ++k) {
        int n = dn[(size_t)wid * 7 + k];
        short8 d = *reinterpret_cast<const short8*>(xt + (size_t)n * 512 + lane * 8);
#pragma unroll
        for (int j = 0; j < 8; ++j) acc[j] += bf2f((unsigned short)d[j]);
    }
    short8 o;
#pragma unroll
    for (int j = 0; j < 8; ++j) o[j] = (short)f2bf(acc[j] * (1.f / 7.f));
    *reinterpret_cast<short8*>(xp + (size_t)wid * 512 + lane * 8) = o;
}

// ---------------------------------------------------------------------------
// Gathered conv via MFMA 16x16x32 bf16. Per wave: 4 vertices, 64x16 output each.
// xin: [vc][16][32*CCH] bf16; hout: [vc][16][64] bf16 (pre-BN); stats: sum[64],sumsq[64]
// ---------------------------------------------------------------------------
template <int CCH>
__global__ __launch_bounds__(256) void conv_mfma(const unsigned short* __restrict__ xin,
                                                 const int* __restrict__ neigh,
                                                 const unsigned short* __restrict__ wfrag,
                                                 unsigned short* __restrict__ hout,
                                                 float* __restrict__ stats,
                                                 int vc, int ngroups) {
    constexpr int C = 32 * CCH;
    constexpr int NCHUNK = 7 * CCH;
    __shared__ __align__(16) unsigned short wlds[NCHUNK * 4 * 64 * 8];
    __shared__ float bsum[128];
    for (int i = threadIdx.x; i < NCHUNK * 256; i += 256)
        reinterpret_cast<short8*>(wlds)[i] = reinterpret_cast<const short8*>(wfrag)[i];
    if (threadIdx.x < 128) bsum[threadIdx.x] = 0.f;
    __syncthreads();

    const int wid = threadIdx.x >> 6;
    const int lane = threadIdx.x & 63;
    const int lb = lane & 15, lg = lane >> 4;

    float ssum[16], ssq[16];
#pragma unroll
    for (int i = 0; i < 16; ++i) { ssum[i] = 0.f; ssq[i] = 0.f; }

    for (int grp = blockIdx.x; grp < ngroups; grp += gridDim.x) {
        const int v0 = grp * 16 + wid * 4;
        f32x4 acc[4][4];
#pragma unroll
        for (int i = 0; i < 4; ++i)
#pragma unroll
            for (int t = 0; t < 4; ++t) acc[i][t] = (f32x4){0.f, 0.f, 0.f, 0.f};

#pragma unroll 1
        for (int k = 0; k < 7; ++k) {
            int n[4];
#pragma unroll
            for (int i = 0; i < 4; ++i) {
                int v = v0 + i;
                n[i] = (v < vc) ? neigh[(size_t)v * 7 + k] : 0;
            }
#pragma unroll
            for (int ch = 0; ch < CCH; ++ch) {
                const int chunk = k * CCH + ch;
                const short8* wp = reinterpret_cast<const short8*>(wlds) + (chunk * 4) * 64 + lane;
                short8 a0 = wp[0];
                short8 a1 = wp[64];
                short8 a2 = wp[128];
                short8 a3 = wp[192];
#pragma unroll
                for (int i = 0; i < 4; ++i) {
                    const short8 b = *reinterpret_cast<const short8*>(
                        xin + (size_t)n[i] * (16 * C) + lb * C + ch * 32 + lg * 8);
                    acc[i][0] = __builtin_amdgcn_mfma_f32_16x16x32_bf16(a0, b, acc[i][0], 0, 0, 0);
                    acc[i][1] = __builtin_amdgcn_mfma_f32_16x16x32_bf16(a1, b, acc[i][1], 0, 0, 0);
                    acc[i][2] = __builtin_amdgcn_mfma_f32_16x16x32_bf16(a2, b, acc[i][2], 0, 0, 0);
                    acc[i][3] = __builtin_amdgcn_mfma_f32_16x16x32_bf16(a3, b, acc[i][3], 0, 0, 0);
                }
            }
        }
        // epilogue: D[o][b], o = t*16 + lg*4 + r, b = lb
#pragma unroll
        for (int i = 0; i < 4; ++i) {
            const int v = v0 + i;
            if (v < vc) {
#pragma unroll
                for (int t = 0; t < 4; ++t) {
                    u16x4 st;
#pragma unroll
                    for (int r = 0; r < 4; ++r) {
                        float f = acc[i][t][r];
                        ssum[t * 4 + r] += f;
                        ssq[t * 4 + r] += f * f;
                        st[r] = f2bf(f);
                    }
                    *reinterpret_cast<u16x4*>(hout + (size_t)v * 1024 + lb * 64 + t * 16 + lg * 4) = st;
                }
            }
        }
    }
    // reduce over the 16 batch lanes
#pragma unroll
    for (int m = 1; m <= 8; m <<= 1) {
#pragma unroll
        for (int i = 0; i < 16; ++i) {
            ssum[i] += __shfl_xor(ssum[i], m, 64);
            ssq[i] += __shfl_xor(ssq[i], m, 64);
        }
    }
    if (lb == 0) {
#pragma unroll
        for (int t = 0; t < 4; ++t)
#pragma unroll
            for (int r = 0; r < 4; ++r) {
                int o = t * 16 + lg * 4 + r;
                atomicAdd(&bsum[o], ssum[t * 4 + r]);
                atomicAdd(&bsum[64 + o], ssq[t * 4 + r]);
            }
    }
    __syncthreads();
    if (threadIdx.x < 128) atomicAdd(&stats[threadIdx.x], bsum[threadIdx.x]);
}

// ---------------------------------------------------------------------------
// BN params: scale = gamma * rsqrt(var+eps); shift = beta - mean*scale
// ---------------------------------------------------------------------------
__global__ void bn_params(const float* __restrict__ stats, const float* __restrict__ gamma,
                          const float* __restrict__ beta, float* __restrict__ params, float inv_n) {
    int o = threadIdx.x;
    if (o < 64) {
        float mean = stats[o] * inv_n;
        float var = stats[64 + o] * inv_n - mean * mean;
        float sc = gamma[o] * rsqrtf(var + 1e-5f);
        params[o] = sc;
        params[64 + o] = beta[o] - mean * sc;
    }
}

// ---------------------------------------------------------------------------
// BN+LReLU apply in-place on h ([v][b][64] bf16)
// ---------------------------------------------------------------------------
__global__ __launch_bounds__(256) void bn_apply(unsigned short* __restrict__ h,
                                                const float* __restrict__ params, int total8) {
    int stride = gridDim.x * blockDim.x;
    int idx0 = blockIdx.x * blockDim.x + threadIdx.x;
    int c0 = (idx0 & 7) * 8;
    float sc[8], sh[8];
#pragma unroll
    for (int j = 0; j < 8; ++j) { sc[j] = params[c0 + j]; sh[j] = params[64 + c0 + j]; }
    for (int idx = idx0; idx < total8; idx += stride) {
        short8 d = *reinterpret_cast<const short8*>(h + (size_t)idx * 8);
        short8 o;
#pragma unroll
        for (int j = 0; j < 8; ++j) {
            float y = sc[j] * bf2f((unsigned short)d[j]) + sh[j];
            y = fmaxf(y, 0.2f * y);
            o[j] = (short)f2bf(y);
        }
        *reinterpret_cast<short8*>(h + (size_t)idx * 8) = o;
    }
}

// ---------------------------------------------------------------------------
// Final: BN2+LReLU on h2[v][b][o] bf16, transpose -> out[b][o][v] f32 via LDS
// ---------------------------------------------------------------------------
__global__ __launch_bounds__(256) void final_out(const unsigned short* __restrict__ h2,
                                                 const float* __restrict__ params,
                                                 float* __restrict__ out, int vc) {
    __shared__ float lds[128 * 65];
    const int t = threadIdx.x;
    const int v0 = blockIdx.x * 64;
    const int sub = t & 15, vloc = t >> 4;
    const int o0 = (sub & 7) * 8;
    float sc[8], sh[8];
#pragma unroll
    for (int j = 0; j < 8; ++j) { sc[j] = params[o0 + j]; sh[j] = params[64 + o0 + j]; }
    for (int c = 0; c < 8; ++c) {
        if (c) __syncthreads();
#pragma unroll
        for (int i = 0; i < 4; ++i) {
            int v = v0 + vloc + 16 * i;
            short8 d = {0, 0, 0, 0, 0, 0, 0, 0};
            if (v < vc)
                d = *reinterpret_cast<const short8*>(h2 + (size_t)v * 1024 + c * 128 + sub * 8);
#pragma unroll
            for (int j = 0; j < 8; ++j) {
                float y = sc[j] * bf2f((unsigned short)d[j]) + sh[j];
                y = fmaxf(y, 0.2f * y);
                lds[(sub * 8 + j) * 65 + vloc + 16 * i] = y;
            }
        }
        __syncthreads();
        for (int q = 0; q < 32; ++q) {
            int idx = t + 256 * q;
            int r = idx >> 6, vv = idx & 63;
            if (v0 + vv < vc)
                out[(size_t)(c * 128 + r) * vc + v0 + vv] = lds[r * 65 + vv];
        }
    }
}

// ---------------------------------------------------------------------------
extern "C" void kernel_launch(void* const* d_in, const int* in_sizes, int n_in,
                              void* d_out, int out_size, void* d_ws, size_t ws_size,
                              hipStream_t stream) {
    const float* x   = (const float*)d_in[0];
    const float* w1  = (const float*)d_in[1];
    const float* g1  = (const float*)d_in[3];
    const float* be1 = (const float*)d_in[4];
    const float* w2  = (const float*)d_in[5];
    const float* g2  = (const float*)d_in[7];
    const float* be2 = (const float*)d_in[8];
    const int* cn    = (const int*)d_in[9];
    const int* dn    = (const int*)d_in[10];
    float* out = (float*)d_out;

    // workspace layout (needs ~210 MB)
    char* ws = (char*)d_ws;
    size_t off = 0;
    auto take = [&](size_t bytes) { size_t o = off; off = (off + bytes + 255) & ~(size_t)255; return o; };
    unsigned short* xp  = (unsigned short*)(ws + take((size_t)VC * 512 * 2));
    unsigned short* h1  = (unsigned short*)(ws + take((size_t)VC * 1024 * 2));
    unsigned short* h2  = (unsigned short*)(ws + take((size_t)VC * 1024 * 2));
    unsigned short* w1f = (unsigned short*)(ws + take(7 * 4 * 64 * 8 * 2));
    unsigned short* w2f = (unsigned short*)(ws + take(14 * 4 * 64 * 8 * 2));
    float* stats        = (float*)(ws + take(256 * 4));       // [sum1|sq1|sum2|sq2]
    float* params       = (float*)(ws + take(256 * 4));       // [sc1|sh1|sc2|sh2]

    // xt (bf16 transposed fine grid) lives in d_out as scratch (dead before final_out)
    unsigned short* xt = (unsigned short*)d_out;

    const float inv_n = 1.0f / (16.0f * (float)VC);
    const int ngroups = (VC + 15) / 16;

    hipMemsetAsync(stats, 0, 256 * 4, stream);
    prep_w<<<32, 256, 0, stream>>>(w1, w2, w1f, w2f);
    transpose_x<<<(VFINE + 15) / 16, 256, 0, stream>>>(x, xt, VFINE);
    pool_k<<<(VC + 3) / 4, 256, 0, stream>>>(xt, dn, xp, VC);
    conv_mfma<1><<<512, 256, 0, stream>>>(xp, cn, w1f, h1, stats, VC, ngroups);
    bn_params<<<1, 64, 0, stream>>>(stats, g1, be1, params, inv_n);
    bn_apply<<<2048, 256, 0, stream>>>(h1, params, VC * 1024 / 8);
    conv_mfma<2><<<512, 256, 0, stream>>>(h1, cn, w2f, h2, stats + 128, VC, ngroups);
    bn_params<<<1, 64, 0, stream>>>(stats + 128, g2, be2, params + 128, inv_n);
    final_out<<<(VC + 63) / 64, 256, 0, stream>>>(h2, params + 128, out, VC);
}

// Round 2
// 514.079 us; speedup vs baseline: 1.1997x; 1.1997x over previous
//
#include <hip/hip_runtime.h>
#include <hip/hip_bf16.h>

// DownBlock: pool(mean over 7 down-neighbors) -> conv1(K=7, 32->64) -> BN+LReLU
//         -> conv2(K=7, 64->64) -> BN+LReLU
// B=16, C_IN=32, C=64, V_FINE=163842, V=40962, K=7.
// Biases b1/b2 are dead: BN's mean subtraction absorbs per-channel constants.

#define B_SZ     16
#define CIN      32
#define CMID     64
#define VFINE    163842
#define VC       40962
#define KNB      7

typedef __attribute__((ext_vector_type(8))) short  short8;   // 8 x bf16 (as i16)
typedef __attribute__((ext_vector_type(4))) float  f32x4;
typedef __attribute__((ext_vector_type(4))) unsigned short u16x4;
typedef __attribute__((ext_vector_type(2))) unsigned short u16x2;

__device__ inline float bf2f(unsigned short u) {
    return __builtin_bit_cast(float, (unsigned int)(((unsigned int)u) << 16));
}
__device__ inline unsigned short f2bf(float f) {
    __hip_bfloat16 h = __float2bfloat16(f);
    return __builtin_bit_cast(unsigned short, h);
}

// ---------------------------------------------------------------------------
// Prep: reorder W into per-lane MFMA A-fragments, bf16.
// Fragment (chunk, otile): lane l, elem j ->  A[o = otile*16 + (l&15)][kk = (l>>4)*8 + j]
// conv1: chunk cc = k (7 chunks), c = kk.        W1[o][c*7+k]
// conv2: chunk cc = k*2 + ch (14), c = ch*32+kk. W2[o][c*7+k]
// ---------------------------------------------------------------------------
__global__ void prep_w(const float* __restrict__ w1, const float* __restrict__ w2,
                       unsigned short* __restrict__ w1f, unsigned short* __restrict__ w2f) {
    int tid = blockIdx.x * blockDim.x + threadIdx.x;
    int stride = gridDim.x * blockDim.x;
    const int total1 = 7 * 4 * 64 * 8;
    for (int idx = tid; idx < total1; idx += stride) {
        int j = idx & 7, l = (idx >> 3) & 63, t = (idx >> 9) & 3, cc = idx >> 11;
        int o = t * 16 + (l & 15);
        int kk = (l >> 4) * 8 + j;
        w1f[idx] = f2bf(w1[o * 224 + kk * 7 + cc]);
    }
    const int total2 = 14 * 4 * 64 * 8;
    for (int idx = tid; idx < total2; idx += stride) {
        int j = idx & 7, l = (idx >> 3) & 63, t = (idx >> 9) & 3, cc = idx >> 11;
        int o = t * 16 + (l & 15);
        int kk = (l >> 4) * 8 + j;
        int k = cc >> 1, ch = cc & 1;
        int c = ch * 32 + kk;
        w2f[idx] = f2bf(w2[o * 448 + c * 7 + k]);
    }
}

// ---------------------------------------------------------------------------
// Transpose x (512 rows x VFINE) f32 -> xt[v][512] bf16.
// 64-vertex tile, two 256-channel phases through a 32KB LDS stage.
// Load:  float4/lane, 256B contiguous per row-instruction. f32->bf16 before LDS.
// LDS:   [256 rows][64 verts] bf16, vert-group XOR swizzle jswz = j ^ ((r>>2)&15)
//        => read phase is <=2-way bank aliased (free).
// Store: per instruction, 2 vertices x 256B contiguous u16x4 chunks.
// ---------------------------------------------------------------------------
__global__ __launch_bounds__(256) void transpose_x(const float* __restrict__ x,
                                                   unsigned short* __restrict__ xt, int vf) {
    __shared__ __align__(16) unsigned short lds[256 * 64];
    const int t = threadIdx.x;
    const int v0 = blockIdx.x * 64;
    const int j  = t & 15;        // load phase: vert group (4 verts)
    const int r0 = t >> 4;        // load phase: row base
    const int lane = t & 63;
    const int wv = (t >> 6) * 16; // read phase: wave's vertex base

#pragma unroll
    for (int p = 0; p < 2; ++p) {
        if (p) __syncthreads();
        // ---- load phase: rows p*256 .. p*256+255, 16 rows per thread
#pragma unroll
        for (int it = 0; it < 16; ++it) {
            int r = r0 + it * 16;          // row within phase
            int row = p * 256 + r;         // global channel row
            int vg = v0 + 4 * j;
            f32x4 d = {0.f, 0.f, 0.f, 0.f};
            if (vg + 3 < vf) {
                d = *reinterpret_cast<const f32x4*>(x + (size_t)row * vf + vg);
            } else {
#pragma unroll
                for (int q = 0; q < 4; ++q)
                    if (vg + q < vf) d[q] = x[(size_t)row * vf + vg + q];
            }
            int jswz = j ^ ((r >> 2) & 15);
            u16x4 s;
#pragma unroll
            for (int q = 0; q < 4; ++q) s[q] = f2bf(d[q]);
            *reinterpret_cast<u16x4*>(lds + r * 64 + jswz * 4) = s;
        }
        __syncthreads();
        // ---- store phase: 2 verts per wave-instruction, 8B/lane
#pragma unroll
        for (int pr = 0; pr < 8; ++pr) {
            int v = wv + pr * 2 + (lane >> 5);   // local vertex 0..63
#pragma unroll
            for (int half = 0; half < 2; ++half) {
                int g = (lane & 31) + 32 * half; // channel group (4 ch)
                u16x4 o;
#pragma unroll
                for (int q = 0; q < 4; ++q) {
                    int r = 4 * g + q;
                    int jswz = (v >> 2) ^ ((r >> 2) & 15);
                    o[q] = lds[r * 64 + jswz * 4 + (v & 3)];
                }
                if (v0 + v < vf)
                    *reinterpret_cast<u16x4*>(xt + (size_t)(v0 + v) * 512 + p * 256 + 4 * g) = o;
            }
        }
    }
}

// ---------------------------------------------------------------------------
// Pool: xp[v][b][c] = mean_k xt[dn[v][k]][b][c]. One wave per coarse vertex.
// ---------------------------------------------------------------------------
__global__ __launch_bounds__(256) void pool_k(const unsigned short* __restrict__ xt,
                                              const int* __restrict__ dn,
                                              unsigned short* __restrict__ xp, int vc) {
    int wid = (blockIdx.x * blockDim.x + threadIdx.x) >> 6;
    int lane = threadIdx.x & 63;
    if (wid >= vc) return;
    float acc[8];
#pragma unroll
    for (int j = 0; j < 8; ++j) acc[j] = 0.f;
#pragma unroll
    for (int k = 0; k < 7; ++k) {
        int n = dn[(size_t)wid * 7 + k];
        short8 d = *reinterpret_cast<const short8*>(xt + (size_t)n * 512 + lane * 8);
#pragma unroll
        for (int j = 0; j < 8; ++j) acc[j] += bf2f((unsigned short)d[j]);
    }
    short8 o;
#pragma unroll
    for (int j = 0; j < 8; ++j) o[j] = (short)f2bf(acc[j] * (1.f / 7.f));
    *reinterpret_cast<short8*>(xp + (size_t)wid * 512 + lane * 8) = o;
}

// ---------------------------------------------------------------------------
// Gathered conv via MFMA 16x16x32 bf16. Per wave: 4 vertices, 64x16 output each.
// xin: [vc][16][32*CCH] bf16; hout: [vc][16][64] bf16 (pre-BN); stats: sum[64],sumsq[64]
// ---------------------------------------------------------------------------
template <int CCH>
__global__ __launch_bounds__(256) void conv_mfma(const unsigned short* __restrict__ xin,
                                                 const int* __restrict__ neigh,
                                                 const unsigned short* __restrict__ wfrag,
                                                 unsigned short* __restrict__ hout,
                                                 float* __restrict__ stats,
                                                 int vc, int ngroups) {
    constexpr int C = 32 * CCH;
    constexpr int NCHUNK = 7 * CCH;
    __shared__ __align__(16) unsigned short wlds[NCHUNK * 4 * 64 * 8];
    __shared__ float bsum[128];
    for (int i = threadIdx.x; i < NCHUNK * 256; i += 256)
        reinterpret_cast<short8*>(wlds)[i] = reinterpret_cast<const short8*>(wfrag)[i];
    if (threadIdx.x < 128) bsum[threadIdx.x] = 0.f;
    __syncthreads();

    const int wid = threadIdx.x >> 6;
    const int lane = threadIdx.x & 63;
    const int lb = lane & 15, lg = lane >> 4;

    float ssum[16], ssq[16];
#pragma unroll
    for (int i = 0; i < 16; ++i) { ssum[i] = 0.f; ssq[i] = 0.f; }

    for (int grp = blockIdx.x; grp < ngroups; grp += gridDim.x) {
        const int v0 = grp * 16 + wid * 4;
        f32x4 acc[4][4];
#pragma unroll
        for (int i = 0; i < 4; ++i)
#pragma unroll
            for (int t = 0; t < 4; ++t) acc[i][t] = (f32x4){0.f, 0.f, 0.f, 0.f};

#pragma unroll 1
        for (int k = 0; k < 7; ++k) {
            int n[4];
#pragma unroll
            for (int i = 0; i < 4; ++i) {
                int v = v0 + i;
                n[i] = (v < vc) ? neigh[(size_t)v * 7 + k] : 0;
            }
#pragma unroll
            for (int ch = 0; ch < CCH; ++ch) {
                const int chunk = k * CCH + ch;
                const short8* wp = reinterpret_cast<const short8*>(wlds) + (chunk * 4) * 64 + lane;
                short8 a0 = wp[0];
                short8 a1 = wp[64];
                short8 a2 = wp[128];
                short8 a3 = wp[192];
#pragma unroll
                for (int i = 0; i < 4; ++i) {
                    const short8 b = *reinterpret_cast<const short8*>(
                        xin + (size_t)n[i] * (16 * C) + lb * C + ch * 32 + lg * 8);
                    acc[i][0] = __builtin_amdgcn_mfma_f32_16x16x32_bf16(a0, b, acc[i][0], 0, 0, 0);
                    acc[i][1] = __builtin_amdgcn_mfma_f32_16x16x32_bf16(a1, b, acc[i][1], 0, 0, 0);
                    acc[i][2] = __builtin_amdgcn_mfma_f32_16x16x32_bf16(a2, b, acc[i][2], 0, 0, 0);
                    acc[i][3] = __builtin_amdgcn_mfma_f32_16x16x32_bf16(a3, b, acc[i][3], 0, 0, 0);
                }
            }
        }
        // epilogue: D[o][b], o = t*16 + lg*4 + r, b = lb
#pragma unroll
        for (int i = 0; i < 4; ++i) {
            const int v = v0 + i;
            if (v < vc) {
#pragma unroll
                for (int t = 0; t < 4; ++t) {
                    u16x4 st;
#pragma unroll
                    for (int r = 0; r < 4; ++r) {
                        float f = acc[i][t][r];
                        ssum[t * 4 + r] += f;
                        ssq[t * 4 + r] += f * f;
                        st[r] = f2bf(f);
                    }
                    *reinterpret_cast<u16x4*>(hout + (size_t)v * 1024 + lb * 64 + t * 16 + lg * 4) = st;
                }
            }
        }
    }
    // reduce over the 16 batch lanes
#pragma unroll
    for (int m = 1; m <= 8; m <<= 1) {
#pragma unroll
        for (int i = 0; i < 16; ++i) {
            ssum[i] += __shfl_xor(ssum[i], m, 64);
            ssq[i] += __shfl_xor(ssq[i], m, 64);
        }
    }
    if (lb == 0) {
#pragma unroll
        for (int t = 0; t < 4; ++t)
#pragma unroll
            for (int r = 0; r < 4; ++r) {
                int o = t * 16 + lg * 4 + r;
                atomicAdd(&bsum[o], ssum[t * 4 + r]);
                atomicAdd(&bsum[64 + o], ssq[t * 4 + r]);
            }
    }
    __syncthreads();
    if (threadIdx.x < 128) atomicAdd(&stats[threadIdx.x], bsum[threadIdx.x]);
}

// ---------------------------------------------------------------------------
// BN params: scale = gamma * rsqrt(var+eps); shift = beta - mean*scale
// ---------------------------------------------------------------------------
__global__ void bn_params(const float* __restrict__ stats, const float* __restrict__ gamma,
                          const float* __restrict__ beta, float* __restrict__ params, float inv_n) {
    int o = threadIdx.x;
    if (o < 64) {
        float mean = stats[o] * inv_n;
        float var = stats[64 + o] * inv_n - mean * mean;
        float sc = gamma[o] * rsqrtf(var + 1e-5f);
        params[o] = sc;
        params[64 + o] = beta[o] - mean * sc;
    }
}

// ---------------------------------------------------------------------------
// BN+LReLU apply in-place on h ([v][b][64] bf16)
// ---------------------------------------------------------------------------
__global__ __launch_bounds__(256) void bn_apply(unsigned short* __restrict__ h,
                                                const float* __restrict__ params, int total8) {
    int stride = gridDim.x * blockDim.x;
    int idx0 = blockIdx.x * blockDim.x + threadIdx.x;
    int c0 = (idx0 & 7) * 8;
    float sc[8], sh[8];
#pragma unroll
    for (int j = 0; j < 8; ++j) { sc[j] = params[c0 + j]; sh[j] = params[64 + c0 + j]; }
    for (int idx = idx0; idx < total8; idx += stride) {
        short8 d = *reinterpret_cast<const short8*>(h + (size_t)idx * 8);
        short8 o;
#pragma unroll
        for (int j = 0; j < 8; ++j) {
            float y = sc[j] * bf2f((unsigned short)d[j]) + sh[j];
            y = fmaxf(y, 0.2f * y);
            o[j] = (short)f2bf(y);
        }
        *reinterpret_cast<short8*>(h + (size_t)idx * 8) = o;
    }
}

// ---------------------------------------------------------------------------
// Final: BN2+LReLU on h2[v][b][o] bf16, transpose -> out[b][o][v] f32 via LDS
// ---------------------------------------------------------------------------
__global__ __launch_bounds__(256) void final_out(const unsigned short* __restrict__ h2,
                                                 const float* __restrict__ params,
                                                 float* __restrict__ out, int vc) {
    __shared__ float lds[128 * 65];
    const int t = threadIdx.x;
    const int v0 = blockIdx.x * 64;
    const int sub = t & 15, vloc = t >> 4;
    const int o0 = (sub & 7) * 8;
    float sc[8], sh[8];
#pragma unroll
    for (int j = 0; j < 8; ++j) { sc[j] = params[o0 + j]; sh[j] = params[64 + o0 + j]; }
    for (int c = 0; c < 8; ++c) {
        if (c) __syncthreads();
#pragma unroll
        for (int i = 0; i < 4; ++i) {
            int v = v0 + vloc + 16 * i;
            short8 d = {0, 0, 0, 0, 0, 0, 0, 0};
            if (v < vc)
                d = *reinterpret_cast<const short8*>(h2 + (size_t)v * 1024 + c * 128 + sub * 8);
#pragma unroll
            for (int j = 0; j < 8; ++j) {
                float y = sc[j] * bf2f((unsigned short)d[j]) + sh[j];
                y = fmaxf(y, 0.2f * y);
                lds[(sub * 8 + j) * 65 + vloc + 16 * i] = y;
            }
        }
        __syncthreads();
        for (int q = 0; q < 32; ++q) {
            int idx = t + 256 * q;
            int r = idx >> 6, vv = idx & 63;
            if (v0 + vv < vc)
                out[(size_t)(c * 128 + r) * vc + v0 + vv] = lds[r * 65 + vv];
        }
    }
}

// ---------------------------------------------------------------------------
extern "C" void kernel_launch(void* const* d_in, const int* in_sizes, int n_in,
                              void* d_out, int out_size, void* d_ws, size_t ws_size,
                              hipStream_t stream) {
    const float* x   = (const float*)d_in[0];
    const float* w1  = (const float*)d_in[1];
    const float* g1  = (const float*)d_in[3];
    const float* be1 = (const float*)d_in[4];
    const float* w2  = (const float*)d_in[5];
    const float* g2  = (const float*)d_in[7];
    const float* be2 = (const float*)d_in[8];
    const int* cn    = (const int*)d_in[9];
    const int* dn    = (const int*)d_in[10];
    float* out = (float*)d_out;

    // workspace layout (needs ~210 MB)
    char* ws = (char*)d_ws;
    size_t off = 0;
    auto take = [&](size_t bytes) { size_t o = off; off = (off + bytes + 255) & ~(size_t)255; return o; };
    unsigned short* xp  = (unsigned short*)(ws + take((size_t)VC * 512 * 2));
    unsigned short* h1  = (unsigned short*)(ws + take((size_t)VC * 1024 * 2));
    unsigned short* h2  = (unsigned short*)(ws + take((size_t)VC * 1024 * 2));
    unsigned short* w1f = (unsigned short*)(ws + take(7 * 4 * 64 * 8 * 2));
    unsigned short* w2f = (unsigned short*)(ws + take(14 * 4 * 64 * 8 * 2));
    float* stats        = (float*)(ws + take(256 * 4));       // [sum1|sq1|sum2|sq2]
    float* params       = (float*)(ws + take(256 * 4));       // [sc1|sh1|sc2|sh2]

    // xt (bf16 transposed fine grid) lives in d_out as scratch (dead before final_out)
    unsigned short* xt = (unsigned short*)d_out;

    const float inv_n = 1.0f / (16.0f * (float)VC);
    const int ngroups = (VC + 15) / 16;

    hipMemsetAsync(stats, 0, 256 * 4, stream);
    prep_w<<<32, 256, 0, stream>>>(w1, w2, w1f, w2f);
    transpose_x<<<(VFINE + 63) / 64, 256, 0, stream>>>(x, xt, VFINE);
    pool_k<<<(VC + 3) / 4, 256, 0, stream>>>(xt, dn, xp, VC);
    conv_mfma<1><<<512, 256, 0, stream>>>(xp, cn, w1f, h1, stats, VC, ngroups);
    bn_params<<<1, 64, 0, stream>>>(stats, g1, be1, params, inv_n);
    bn_apply<<<2048, 256, 0, stream>>>(h1, params, VC * 1024 / 8);
    conv_mfma<2><<<512, 256, 0, stream>>>(h1, cn, w2f, h2, stats + 128, VC, ngroups);
    bn_params<<<1, 64, 0, stream>>>(stats + 128, g2, be2, params + 128, inv_n);
    final_out<<<(VC + 63) / 64, 256, 0, stream>>>(h2, params + 128, out, VC);
}